// Round 4
// baseline (397.718 us; speedup 1.0000x reference)
//
#include <hip/hip_runtime.h>
#include <hip/hip_bf16.h>

typedef __attribute__((ext_vector_type(8))) __bf16 bf16x8;
typedef __attribute__((ext_vector_type(4))) float f32x4;

#define BM 128
#define BN 128
#define BKF 64              // f32 k-elements staged per K-step
#define DDIM 256
#define KCENT 1024
#define NSTEP (DDIM / BKF)  // 4

union FragU { uint4 u; bf16x8 f; };

__device__ inline unsigned int pk2(float lo, float hi) {
    union { __hip_bfloat16 h; unsigned short u; } a, b;
    a.h = __float2bfloat16(lo);
    b.h = __float2bfloat16(hi);
    return (unsigned int)a.u | ((unsigned int)b.u << 16);
}

// 128x128 tile, 4 waves (2x2 of 64x64), mfma_f32_16x16x32_bf16, NT-GEMM:
// cross[i][j] = sum_d x[i][d]*centers[j][d].
// R3 changes vs baseline (109 us, latency-bound: Occ 20%, hbm 31%):
//  - T1 bijective XCD swizzle: all 8 N-blocks of an M-panel land on ONE
//    XCD's L2 -> x-panel fetched from HBM once (FETCH 132 MB -> ~45 MB).
//  - __launch_bounds__(256,4): LDS 35.5K x4 = 145K <= 160K, VGPR<=128 ->
//    4 blocks/CU (was 2) for 2x TLP.
//  - Software pipeline: K-step ks+1 global loads issue after barrier 2,
//    BEFORE the MFMA block, into the same va/vb regs (old values dead
//    after pk2) -> loads fly under MFMA instead of serializing.
__global__ __launch_bounds__(256, 4) void rbf_kernel(
    const float* __restrict__ x,
    const float* __restrict__ centers,
    const float* __restrict__ sigmas,
    float* __restrict__ out, int Brows)
{
    __shared__ __align__(16) unsigned char ldsA[BM * 128];
    __shared__ __align__(16) unsigned char ldsB[BN * 128];
    __shared__ float s_redA[256];
    __shared__ float s_redB[256];
    __shared__ float s_x2[BM];
    __shared__ float s_c2[BN];
    __shared__ float s_scale[BN];

    const int t = threadIdx.x;

    // T1 bijective XCD swizzle (nwg = nwgM*8, always %8==0): hw block bx on
    // XCD bx&7; logical id = xcd*nwgM + bx>>3 -> each XCD owns a contiguous
    // run of M-panels with all 8 N-tiles consecutive -> x-panel L2-resident.
    const int nwgM = Brows >> 7;
    const int bx = blockIdx.x;
    const int lid = (bx & 7) * nwgM + (bx >> 3);
    const int mrow0 = (lid >> 3) * BM;
    const int ncol0 = (lid & 7) * BN;

    // staging role: row r (0..127), half h (32 f32 = 128 B)
    const int r = t >> 1;
    const int h = t & 1;
    // compute role
    const int lane = t & 63;
    const int wave = t >> 6;
    const int wr = wave >> 1, wc = wave & 1;
    const int q = lane >> 4, r16 = lane & 15;

    f32x4 acc[4][4];
#pragma unroll
    for (int i = 0; i < 4; ++i)
#pragma unroll
        for (int j = 0; j < 4; ++j)
            acc[i][j] = (f32x4){0.f, 0.f, 0.f, 0.f};

    float sa = 0.f, sb = 0.f;  // f32 sum-of-squares for x-row-half / center-row-half

    const float4* __restrict__ xg = (const float4*)(x + (size_t)(mrow0 + r) * DDIM);
    const float4* __restrict__ cg = (const float4*)(centers + (size_t)(ncol0 + r) * DDIM);

    float4 va[8], vb[8];
    // prologue: K-step 0 loads
    {
        const int base = h * 8;
#pragma unroll
        for (int c = 0; c < 8; ++c) { va[c] = xg[base + c]; vb[c] = cg[base + c]; }
    }

    for (int ks = 0; ks < NSTEP; ++ks) {
        // f32 sum-of-squares (exact inputs, not bf16-rounded) — first consumer
        // of the loads; the implicit vmcnt wait for step ks lands here, after
        // step ks-1's MFMAs covered the latency.
#pragma unroll
        for (int c = 0; c < 8; ++c) {
            sa += va[c].x * va[c].x + va[c].y * va[c].y + va[c].z * va[c].z + va[c].w * va[c].w;
            sb += vb[c].x * vb[c].x + vb[c].y * vb[c].y + vb[c].z * vb[c].z + vb[c].w * vb[c].w;
        }

        __syncthreads();  // previous iteration's fragment reads complete

        // ---- convert + swizzled LDS write: 4x 16B chunks per operand ----
#pragma unroll
        for (int c = 0; c < 4; ++c) {
            uint4 pa, pb;
            pa.x = pk2(va[2 * c].x, va[2 * c].y);
            pa.y = pk2(va[2 * c].z, va[2 * c].w);
            pa.z = pk2(va[2 * c + 1].x, va[2 * c + 1].y);
            pa.w = pk2(va[2 * c + 1].z, va[2 * c + 1].w);
            pb.x = pk2(vb[2 * c].x, vb[2 * c].y);
            pb.y = pk2(vb[2 * c].z, vb[2 * c].w);
            pb.z = pk2(vb[2 * c + 1].x, vb[2 * c + 1].y);
            pb.w = pk2(vb[2 * c + 1].z, vb[2 * c + 1].w);
            const int slot = ((h * 4 + c) ^ (r & 7)) << 4;
            *(uint4*)(ldsA + r * 128 + slot) = pa;
            *(uint4*)(ldsB + r * 128 + slot) = pb;
        }

        __syncthreads();

        // ---- pipelined prefetch: issue K-step ks+1 loads into the same
        //      registers (old values consumed by pk2 above) so they overlap
        //      the ds_read + MFMA below and the next barrier. ----
        if (ks + 1 < NSTEP) {
            const int base = (ks + 1) * (BKF / 4) + h * 8;
#pragma unroll
            for (int c = 0; c < 8; ++c) { va[c] = xg[base + c]; vb[c] = cg[base + c]; }
        }

        // ---- fragment reads + 32 MFMAs ----
        FragU bfr[4][2];
#pragma unroll
        for (int fn = 0; fn < 4; ++fn) {
            const int row = wc * 64 + fn * 16 + r16;
#pragma unroll
            for (int kk = 0; kk < 2; ++kk) {
                const int slot = ((kk * 4 + q) ^ (row & 7)) << 4;
                bfr[fn][kk].u = *(const uint4*)(ldsB + row * 128 + slot);
            }
        }
#pragma unroll
        for (int fm = 0; fm < 4; ++fm) {
            const int row = wr * 64 + fm * 16 + r16;
            FragU afr[2];
#pragma unroll
            for (int kk = 0; kk < 2; ++kk) {
                const int slot = ((kk * 4 + q) ^ (row & 7)) << 4;
                afr[kk].u = *(const uint4*)(ldsA + row * 128 + slot);
            }
#pragma unroll
            for (int fn = 0; fn < 4; ++fn) {
                acc[fm][fn] = __builtin_amdgcn_mfma_f32_16x16x32_bf16(
                    afr[0].f, bfr[fn][0].f, acc[fm][fn], 0, 0, 0);
                acc[fm][fn] = __builtin_amdgcn_mfma_f32_16x16x32_bf16(
                    afr[1].f, bfr[fn][1].f, acc[fm][fn], 0, 0, 0);
            }
        }
    }

    // ---- reduce half-row sums -> x2[128], c2[128], scale[128] ----
    s_redA[t] = sa;
    s_redB[t] = sb;
    __syncthreads();
    if (t < 128) {
        s_x2[t] = s_redA[2 * t] + s_redA[2 * t + 1];
        s_c2[t] = s_redB[2 * t] + s_redB[2 * t + 1];
        const float sg = sigmas[ncol0 + t];
        s_scale[t] = -0.5f / (sg * sg);
    }
    __syncthreads();

    // ---- epilogue: sqdist = x2 + c2 - 2*cross; out = exp(scale*sqdist) ----
    // C/D layout (m89-verified): col = lane&15, row = (lane>>4)*4 + reg
    float* outp = out + (size_t)mrow0 * KCENT + ncol0;
#pragma unroll
    for (int fm = 0; fm < 4; ++fm) {
#pragma unroll
        for (int fn = 0; fn < 4; ++fn) {
            const int il = wr * 64 + fm * 16 + q * 4;
            const int j = wc * 64 + fn * 16 + r16;
            const float c2v = s_c2[j];
            const float sc = s_scale[j];
#pragma unroll
            for (int rg = 0; rg < 4; ++rg) {
                const float sq = s_x2[il + rg] + c2v - 2.0f * acc[fm][fn][rg];
                outp[(size_t)(il + rg) * KCENT + j] = __expf(sq * sc);
            }
        }
    }
}

extern "C" void kernel_launch(void* const* d_in, const int* in_sizes, int n_in,
                              void* d_out, int out_size, void* d_ws, size_t ws_size,
                              hipStream_t stream) {
    const float* x = (const float*)d_in[0];
    const float* centers = (const float*)d_in[1];
    const float* sigmas = (const float*)d_in[2];
    float* out = (float*)d_out;

    const int Brows = in_sizes[0] / DDIM;          // 32768
    const int nwg = (Brows / BM) * (KCENT / BN);   // 2048, 1D grid; kernel
                                                   // decodes with XCD swizzle
    rbf_kernel<<<dim3(nwg), dim3(256), 0, stream>>>(x, centers, sigmas, out, Brows);
}

// Round 5
// 221.936 us; speedup vs baseline: 1.7920x; 1.7920x over previous
//
#include <hip/hip_runtime.h>
#include <hip/hip_bf16.h>

typedef __attribute__((ext_vector_type(8))) __bf16 bf16x8;
typedef __attribute__((ext_vector_type(4))) float f32x4;

#define BM 128
#define BN 128
#define BKF 64              // f32 k-elements staged per K-step
#define DDIM 256
#define KCENT 1024
#define NSTEP (DDIM / BKF)  // 4

union FragU { uint4 u; bf16x8 f; };

__device__ inline unsigned int pk2(float lo, float hi) {
    union { __hip_bfloat16 h; unsigned short u; } a, b;
    a.h = __float2bfloat16(lo);
    b.h = __float2bfloat16(hi);
    return (unsigned int)a.u | ((unsigned int)b.u << 16);
}

// 128x128 tile, 4 waves (2x2 of 64x64), mfma_f32_16x16x32_bf16, NT-GEMM:
// cross[i][j] = sum_d x[i][d]*centers[j][d].
// R4: R3 structure with __launch_bounds__(256,2).
//   R3's (256,4) forced VGPR=64 -> accumulator/staging spill to scratch
//   (WRITE_SIZE 131->800 MB, dur 109->278 us). This kernel's live state
//   (acc 64 + pipelined va/vb 64 + frags ~40) needs ~190 VGPR; (256,2)
//   caps at 256 -> no spill, 2 blocks/CU.
// Kept from R3 (effects were masked by the spill):
//  - T1 bijective XCD swizzle: resident set/XCD = ~8 x-panels (1MB) +
//    centers (1MB) <= 4MB L2 -> x re-reads are L2 hits (FETCH 132->~50MB).
//  - Register pipeline: ks+1 global loads issue before ks's MFMA block;
//    the vmcnt wait lands next iteration after MFMA+barriers covered
//    the latency.
__global__ __launch_bounds__(256, 2) void rbf_kernel(
    const float* __restrict__ x,
    const float* __restrict__ centers,
    const float* __restrict__ sigmas,
    float* __restrict__ out, int Brows)
{
    __shared__ __align__(16) unsigned char ldsA[BM * 128];
    __shared__ __align__(16) unsigned char ldsB[BN * 128];
    __shared__ float s_redA[256];
    __shared__ float s_redB[256];
    __shared__ float s_x2[BM];
    __shared__ float s_c2[BN];
    __shared__ float s_scale[BN];

    const int t = threadIdx.x;

    // T1 bijective XCD swizzle (nwg = nwgM*8, always %8==0): hw block bx on
    // XCD bx&7; logical id = xcd*nwgM + bx>>3 -> each XCD owns a contiguous
    // run of M-panels with all 8 N-tiles consecutive -> x-panel L2-resident.
    const int nwgM = Brows >> 7;
    const int bx = blockIdx.x;
    const int lid = (bx & 7) * nwgM + (bx >> 3);
    const int mrow0 = (lid >> 3) * BM;
    const int ncol0 = (lid & 7) * BN;

    // staging role: row r (0..127), half h (32 f32 = 128 B)
    const int r = t >> 1;
    const int h = t & 1;
    // compute role
    const int lane = t & 63;
    const int wave = t >> 6;
    const int wr = wave >> 1, wc = wave & 1;
    const int q = lane >> 4, r16 = lane & 15;

    f32x4 acc[4][4];
#pragma unroll
    for (int i = 0; i < 4; ++i)
#pragma unroll
        for (int j = 0; j < 4; ++j)
            acc[i][j] = (f32x4){0.f, 0.f, 0.f, 0.f};

    float sa = 0.f, sb = 0.f;  // f32 sum-of-squares for x-row-half / center-row-half

    const float4* __restrict__ xg = (const float4*)(x + (size_t)(mrow0 + r) * DDIM);
    const float4* __restrict__ cg = (const float4*)(centers + (size_t)(ncol0 + r) * DDIM);

    float4 va[8], vb[8];
    // prologue: K-step 0 loads
    {
        const int base = h * 8;
#pragma unroll
        for (int c = 0; c < 8; ++c) { va[c] = xg[base + c]; vb[c] = cg[base + c]; }
    }

    for (int ks = 0; ks < NSTEP; ++ks) {
        // f32 sum-of-squares (exact inputs, not bf16-rounded) — first consumer
        // of the loads; the implicit vmcnt wait for step ks lands here, after
        // step ks-1's MFMAs covered the latency.
#pragma unroll
        for (int c = 0; c < 8; ++c) {
            sa += va[c].x * va[c].x + va[c].y * va[c].y + va[c].z * va[c].z + va[c].w * va[c].w;
            sb += vb[c].x * vb[c].x + vb[c].y * vb[c].y + vb[c].z * vb[c].z + vb[c].w * vb[c].w;
        }

        __syncthreads();  // previous iteration's fragment reads complete

        // ---- convert + swizzled LDS write: 4x 16B chunks per operand ----
#pragma unroll
        for (int c = 0; c < 4; ++c) {
            uint4 pa, pb;
            pa.x = pk2(va[2 * c].x, va[2 * c].y);
            pa.y = pk2(va[2 * c].z, va[2 * c].w);
            pa.z = pk2(va[2 * c + 1].x, va[2 * c + 1].y);
            pa.w = pk2(va[2 * c + 1].z, va[2 * c + 1].w);
            pb.x = pk2(vb[2 * c].x, vb[2 * c].y);
            pb.y = pk2(vb[2 * c].z, vb[2 * c].w);
            pb.z = pk2(vb[2 * c + 1].x, vb[2 * c + 1].y);
            pb.w = pk2(vb[2 * c + 1].z, vb[2 * c + 1].w);
            const int slot = ((h * 4 + c) ^ (r & 7)) << 4;
            *(uint4*)(ldsA + r * 128 + slot) = pa;
            *(uint4*)(ldsB + r * 128 + slot) = pb;
        }

        __syncthreads();

        // ---- pipelined prefetch: issue K-step ks+1 loads into the same
        //      registers (old values consumed by pk2 above) so they overlap
        //      the ds_read + MFMA below and the next barrier. ----
        if (ks + 1 < NSTEP) {
            const int base = (ks + 1) * (BKF / 4) + h * 8;
#pragma unroll
            for (int c = 0; c < 8; ++c) { va[c] = xg[base + c]; vb[c] = cg[base + c]; }
        }

        // ---- fragment reads + 32 MFMAs ----
        FragU bfr[4][2];
#pragma unroll
        for (int fn = 0; fn < 4; ++fn) {
            const int row = wc * 64 + fn * 16 + r16;
#pragma unroll
            for (int kk = 0; kk < 2; ++kk) {
                const int slot = ((kk * 4 + q) ^ (row & 7)) << 4;
                bfr[fn][kk].u = *(const uint4*)(ldsB + row * 128 + slot);
            }
        }
#pragma unroll
        for (int fm = 0; fm < 4; ++fm) {
            const int row = wr * 64 + fm * 16 + r16;
            FragU afr[2];
#pragma unroll
            for (int kk = 0; kk < 2; ++kk) {
                const int slot = ((kk * 4 + q) ^ (row & 7)) << 4;
                afr[kk].u = *(const uint4*)(ldsA + row * 128 + slot);
            }
#pragma unroll
            for (int fn = 0; fn < 4; ++fn) {
                acc[fm][fn] = __builtin_amdgcn_mfma_f32_16x16x32_bf16(
                    afr[0].f, bfr[fn][0].f, acc[fm][fn], 0, 0, 0);
                acc[fm][fn] = __builtin_amdgcn_mfma_f32_16x16x32_bf16(
                    afr[1].f, bfr[fn][1].f, acc[fm][fn], 0, 0, 0);
            }
        }
    }

    // ---- reduce half-row sums -> x2[128], c2[128], scale[128] ----
    s_redA[t] = sa;
    s_redB[t] = sb;
    __syncthreads();
    if (t < 128) {
        s_x2[t] = s_redA[2 * t] + s_redA[2 * t + 1];
        s_c2[t] = s_redB[2 * t] + s_redB[2 * t + 1];
        const float sg = sigmas[ncol0 + t];
        s_scale[t] = -0.5f / (sg * sg);
    }
    __syncthreads();

    // ---- epilogue: sqdist = x2 + c2 - 2*cross; out = exp(scale*sqdist) ----
    // C/D layout (m89-verified): col = lane&15, row = (lane>>4)*4 + reg
    float* outp = out + (size_t)mrow0 * KCENT + ncol0;
#pragma unroll
    for (int fm = 0; fm < 4; ++fm) {
#pragma unroll
        for (int fn = 0; fn < 4; ++fn) {
            const int il = wr * 64 + fm * 16 + q * 4;
            const int j = wc * 64 + fn * 16 + r16;
            const float c2v = s_c2[j];
            const float sc = s_scale[j];
#pragma unroll
            for (int rg = 0; rg < 4; ++rg) {
                const float sq = s_x2[il + rg] + c2v - 2.0f * acc[fm][fn][rg];
                outp[(size_t)(il + rg) * KCENT + j] = __expf(sq * sc);
            }
        }
    }
}

extern "C" void kernel_launch(void* const* d_in, const int* in_sizes, int n_in,
                              void* d_out, int out_size, void* d_ws, size_t ws_size,
                              hipStream_t stream) {
    const float* x = (const float*)d_in[0];
    const float* centers = (const float*)d_in[1];
    const float* sigmas = (const float*)d_in[2];
    float* out = (float*)d_out;

    const int Brows = in_sizes[0] / DDIM;          // 32768
    const int nwg = (Brows / BM) * (KCENT / BN);   // 2048, 1D grid; kernel
                                                   // decodes with XCD swizzle
    rbf_kernel<<<dim3(nwg), dim3(256), 0, stream>>>(x, centers, sigmas, out, Brows);
}

// Round 6
// 190.908 us; speedup vs baseline: 2.0833x; 1.1625x over previous
//
#include <hip/hip_runtime.h>
#include <hip/hip_bf16.h>

typedef __attribute__((ext_vector_type(8))) __bf16 bf16x8;
typedef __attribute__((ext_vector_type(4))) float f32x4;

#define DDIM 256
#define KCENT 1024
#define BM 128
#define BN 128

union FragU { uint4 u; bf16x8 f; };

__device__ __forceinline__ unsigned int pk2(float lo, float hi) {
    union { __hip_bfloat16 h; unsigned short u; } a, b;
    a.h = __float2bfloat16(lo);
    b.h = __float2bfloat16(hi);
    return (unsigned int)a.u | ((unsigned int)b.u << 16);
}

// async global->LDS, 16B per lane (global_load_lds_dwordx4).
// LDS dest is wave-uniform base + lane*16 (HW); global src is per-lane.
__device__ __forceinline__ void gl_lds16(const void* g, void* l) {
    __builtin_amdgcn_global_load_lds(
        (const __attribute__((address_space(1))) unsigned int*)g,
        (__attribute__((address_space(3))) unsigned int*)l,
        16, 0, 0);
}

// ---------------------------------------------------------------------------
// Kernel 1: f32 -> bf16 conversion + exact f32 row stats.
//   x[Brows][256] -> xbf;  x2[r] = ||x_r||^2
//   centers[1024][256] -> cbf;  c2s[c] = { ||c||^2, -0.5/sigma^2 }
// One wave per row: lane loads float4 (16B coalesced), shuffle-reduce sumsq,
// packs 4 bf16 as uint2 (8B coalesced store).
// ---------------------------------------------------------------------------
__global__ void rbf_prep(const float* __restrict__ x,
                         const float* __restrict__ centers,
                         const float* __restrict__ sigmas,
                         __bf16* __restrict__ xbf, __bf16* __restrict__ cbf,
                         float* __restrict__ x2, float2* __restrict__ c2s,
                         int Brows)
{
    const int wave = threadIdx.x >> 6, lane = threadIdx.x & 63;
    const int row = blockIdx.x * 4 + wave;
    const bool isx = row < Brows;
    const int r = isx ? row : row - Brows;

    const float4* __restrict__ src =
        (const float4*)((isx ? x : centers) + (size_t)r * DDIM);
    const float4 v = src[lane];
    float s = v.x * v.x + v.y * v.y + v.z * v.z + v.w * v.w;
#pragma unroll
    for (int m = 1; m < 64; m <<= 1) s += __shfl_xor(s, m, 64);

    uint2 p;
    p.x = pk2(v.x, v.y);
    p.y = pk2(v.z, v.w);
    uint2* dst = (uint2*)((isx ? xbf : cbf) + (size_t)r * DDIM);
    dst[lane] = p;

    if (lane == 0) {
        if (isx) {
            x2[r] = s;
        } else {
            const float sg = sigmas[r];
            c2s[r] = make_float2(s, -0.5f / (sg * sg));
        }
    }
}

// ---------------------------------------------------------------------------
// Kernel 2: m97-shape bf16 NT-GEMM + RBF epilogue.
// 128x128 tile, 4 waves (2x2 of 64x64), BK=64 bf16, 4 K-steps.
// Staging: global_load_lds width=16, LINEAR LDS dest; the XOR swizzle
// (slot ^= row&7, 16B units) is applied by permuting the per-lane GLOBAL
// source chunk (rule #21: both-sides-or-neither). Fragment reads use the
// identical involution -> same conflict-free pattern R4 measured (0 confl).
// MFMA + C/D epilogue mapping verbatim from R4 (absmax 0.0 on HW, twice).
// ---------------------------------------------------------------------------
__global__ void rbf_gemm(const __bf16* __restrict__ xbf,
                         const __bf16* __restrict__ cbf,
                         const float* __restrict__ x2,
                         const float2* __restrict__ c2s,
                         float* __restrict__ out, int Brows)
{
    __shared__ __align__(16) unsigned char ldsA[BM * 128];
    __shared__ __align__(16) unsigned char ldsB[BN * 128];

    const int t = threadIdx.x;

    // T1 bijective XCD swizzle (nwg = nwgM*8): each XCD owns a contiguous
    // run of M-panels with all 8 N-tiles consecutive -> x-panel L2-resident
    // (R4 measured FETCH 132 -> 27 MB with this).
    const int nwgM = Brows >> 7;
    const int bx = blockIdx.x;
    const int lid = (bx & 7) * nwgM + (bx >> 3);
    const int mrow0 = (lid >> 3) * BM;
    const int ncol0 = (lid & 7) * BN;

    const int lane = t & 63, wave = t >> 6;
    const int wr = wave >> 1, wc = wave & 1;
    const int q = lane >> 4, r16 = lane & 15;

    // staging role: issue i covers LDS [i*4096, i*4096+4096); thread t's 16B
    // lands at i*4096 + t*16 -> row = i*32 + (t>>3), slot = t&7.
    const int srow = t >> 3;
    const int sslot = t & 7;
    const char* __restrict__ xg = (const char*)xbf;
    const char* __restrict__ cg = (const char*)cbf;

    f32x4 acc[4][4];
#pragma unroll
    for (int i = 0; i < 4; ++i)
#pragma unroll
        for (int j = 0; j < 4; ++j)
            acc[i][j] = (f32x4){0.f, 0.f, 0.f, 0.f};

    for (int ks = 0; ks < 4; ++ks) {
        // ---- stage A,B tiles: 8 global_load_lds_dwordx4 per wave ----
#pragma unroll
        for (int i = 0; i < 4; ++i) {
            const int row = i * 32 + srow;
            const int chunk = sslot ^ (row & 7);   // pre-swizzled source
            const size_t gbA = (size_t)(mrow0 + row) * 512 + (size_t)ks * 128 + (size_t)chunk * 16;
            const size_t gbB = (size_t)(ncol0 + row) * 512 + (size_t)ks * 128 + (size_t)chunk * 16;
            const int lbase = i * 4096 + wave * 1024;  // wave-uniform; HW adds lane*16
            gl_lds16(xg + gbA, ldsA + lbase);
            gl_lds16(cg + gbB, ldsB + lbase);
        }
        __syncthreads();   // drains vmcnt (loads landed) per HIP barrier semantics

        // ---- fragment reads (swizzled) + 32 MFMAs ----
        FragU bfr[4][2];
#pragma unroll
        for (int fn = 0; fn < 4; ++fn) {
            const int row = wc * 64 + fn * 16 + r16;
#pragma unroll
            for (int kk = 0; kk < 2; ++kk) {
                const int slot = ((kk * 4 + q) ^ (row & 7)) << 4;
                bfr[fn][kk].u = *(const uint4*)(ldsB + row * 128 + slot);
            }
        }
#pragma unroll
        for (int fm = 0; fm < 4; ++fm) {
            const int row = wr * 64 + fm * 16 + r16;
            FragU afr[2];
#pragma unroll
            for (int kk = 0; kk < 2; ++kk) {
                const int slot = ((kk * 4 + q) ^ (row & 7)) << 4;
                afr[kk].u = *(const uint4*)(ldsA + row * 128 + slot);
            }
#pragma unroll
            for (int fn = 0; fn < 4; ++fn) {
                acc[fm][fn] = __builtin_amdgcn_mfma_f32_16x16x32_bf16(
                    afr[0].f, bfr[fn][0].f, acc[fm][fn], 0, 0, 0);
                acc[fm][fn] = __builtin_amdgcn_mfma_f32_16x16x32_bf16(
                    afr[1].f, bfr[fn][1].f, acc[fm][fn], 0, 0, 0);
            }
        }
        __syncthreads();
    }

    // ---- epilogue: sqdist = x2 + c2 - 2*cross; out = exp(scale*sqdist) ----
    // C/D layout (m89-verified): col = lane&15, row = (lane>>4)*4 + reg.
    // x2/c2s are tiny, L2-hot; float4 / float2 loads, no extra barrier.
    float* outp = out + (size_t)mrow0 * KCENT + ncol0;
#pragma unroll
    for (int fm = 0; fm < 4; ++fm) {
        const int il = wr * 64 + fm * 16 + q * 4;
        const f32x4 xv = *(const f32x4*)&x2[mrow0 + il];
#pragma unroll
        for (int fn = 0; fn < 4; ++fn) {
            const int j = wc * 64 + fn * 16 + r16;
            const float2 cs = c2s[ncol0 + j];
#pragma unroll
            for (int rg = 0; rg < 4; ++rg) {
                const float sq = xv[rg] + cs.x - 2.0f * acc[fm][fn][rg];
                outp[(size_t)(il + rg) * KCENT + j] = __expf(sq * cs.y);
            }
        }
    }
}

extern "C" void kernel_launch(void* const* d_in, const int* in_sizes, int n_in,
                              void* d_out, int out_size, void* d_ws, size_t ws_size,
                              hipStream_t stream) {
    const float* x = (const float*)d_in[0];
    const float* centers = (const float*)d_in[1];
    const float* sigmas = (const float*)d_in[2];
    float* out = (float*)d_out;

    const int Brows = in_sizes[0] / DDIM;  // 32768

    // workspace layout (bytes): xbf | cbf | x2 | c2s  (~17.5 MB total)
    char* ws = (char*)d_ws;
    __bf16* xbf = (__bf16*)ws;
    __bf16* cbf = (__bf16*)(ws + (size_t)Brows * DDIM * 2);
    float* x2 = (float*)(ws + (size_t)Brows * DDIM * 2 + (size_t)KCENT * DDIM * 2);
    float2* c2s = (float2*)((char*)x2 + (size_t)Brows * 4);

    rbf_prep<<<dim3((Brows + KCENT) / 4), dim3(256), 0, stream>>>(
        x, centers, sigmas, xbf, cbf, x2, c2s, Brows);

    const int nwg = (Brows / BM) * (KCENT / BN);  // 2048
    rbf_gemm<<<dim3(nwg), dim3(256), 0, stream>>>(xbf, cbf, x2, c2s, out, Brows);
}

// Round 7
// 180.432 us; speedup vs baseline: 2.2043x; 1.0581x over previous
//
#include <hip/hip_runtime.h>
#include <hip/hip_bf16.h>

typedef __attribute__((ext_vector_type(8))) __bf16 bf16x8;
typedef __attribute__((ext_vector_type(4))) float f32x4;

#define DDIM 256
#define KCENT 1024
#define BM 128
#define BN 128
#define ROWB 512   // LDS row stride: 256 bf16 = 512 B (full K per row)

union FragU { uint4 u; bf16x8 f; };

__device__ __forceinline__ unsigned int pk2(float lo, float hi) {
    union { __hip_bfloat16 h; unsigned short u; } a, b;
    a.h = __float2bfloat16(lo);
    b.h = __float2bfloat16(hi);
    return (unsigned int)a.u | ((unsigned int)b.u << 16);
}

// async global->LDS, 16B per lane (global_load_lds_dwordx4).
// LDS dest = wave-uniform base + lane*16 (HW); global src is per-lane.
__device__ __forceinline__ void gl_lds16(const void* g, void* l) {
    __builtin_amdgcn_global_load_lds(
        (const __attribute__((address_space(1))) unsigned int*)g,
        (__attribute__((address_space(3))) unsigned int*)l,
        16, 0, 0);
}

// ---------------------------------------------------------------------------
// Kernel 1 (unchanged from R5, verified): f32 -> bf16 + exact f32 row stats.
// ---------------------------------------------------------------------------
__global__ __launch_bounds__(256) void rbf_prep(
    const float* __restrict__ x, const float* __restrict__ centers,
    const float* __restrict__ sigmas,
    __bf16* __restrict__ xbf, __bf16* __restrict__ cbf,
    float* __restrict__ x2, float2* __restrict__ c2s, int Brows)
{
    const int wave = threadIdx.x >> 6, lane = threadIdx.x & 63;
    const int row = blockIdx.x * 4 + wave;
    const bool isx = row < Brows;
    const int r = isx ? row : row - Brows;

    const float4* __restrict__ src =
        (const float4*)((isx ? x : centers) + (size_t)r * DDIM);
    const float4 v = src[lane];
    float s = v.x * v.x + v.y * v.y + v.z * v.z + v.w * v.w;
#pragma unroll
    for (int m = 1; m < 64; m <<= 1) s += __shfl_xor(s, m, 64);

    uint2 p;
    p.x = pk2(v.x, v.y);
    p.y = pk2(v.z, v.w);
    uint2* dst = (uint2*)((isx ? xbf : cbf) + (size_t)r * DDIM);
    dst[lane] = p;

    if (lane == 0) {
        if (isx) {
            x2[r] = s;
        } else {
            const float sg = sigmas[r];
            c2s[r] = make_float2(s, -0.5f / (sg * sg));
        }
    }
}

// ---------------------------------------------------------------------------
// Kernel 2 (R6 restructure): one block per 128-row M-panel, N-loop inside.
// grid = Brows/128 = 256 = 1 block/CU; 512 threads (8 waves, 4M x 2N tiles
// of 32x64). A[128][256]bf16 staged in LDS ONCE (64KB); per N-tile, B tile
// (64KB) staged via gl_lds issued EARLY (under previous tile's epilogue).
// Swizzle involution (chunk ^= row&7, 16B units) applied on gl_lds SOURCE
// and ds_read identically (rule #21) -> conflict-free (R4/R5: 0 conflicts).
// MFMA fragment + C/D mappings verbatim from R4/R5 (absmax 0.0 on HW, 3x).
// Writes per block = contiguous 512KB; stores pace the loop at HBM rate.
// ---------------------------------------------------------------------------
__global__ __launch_bounds__(512, 2) void rbf_gemm(
    const __bf16* __restrict__ xbf, const __bf16* __restrict__ cbf,
    const float* __restrict__ x2, const float2* __restrict__ c2s,
    float* __restrict__ out)
{
    __shared__ __align__(16) unsigned char ldsA[BM * ROWB];  // 64 KB
    __shared__ __align__(16) unsigned char ldsB[BN * ROWB];  // 64 KB

    const int t = threadIdx.x;
    const int lane = t & 63, wave = t >> 6;
    const int wr = wave >> 1, wc = wave & 1;       // 4 x 2 wave grid
    const int q = lane >> 4, r16 = lane & 15;
    const int mrow0 = blockIdx.x * BM;

    const char* __restrict__ xg = (const char*)xbf;
    const char* __restrict__ cg = (const char*)cbf;

    // staging role: issue i covers rows [i*16, i*16+16); thread t's 16B lands
    // at LDS i*8192 + t*16 -> row = i*16 + (t>>5), chunk = t&31 (32/row).
    const int srow = t >> 5;
    const int schunk = t & 31;

    // ---- stage A once ----
#pragma unroll
    for (int i = 0; i < 8; ++i) {
        const int row = i * 16 + srow;
        const int chunk = schunk ^ (row & 7);
        gl_lds16(xg + (size_t)(mrow0 + row) * ROWB + chunk * 16,
                 ldsA + i * 8192 + (wave << 10));
    }
    // ---- stage B[0] ----
#pragma unroll
    for (int i = 0; i < 8; ++i) {
        const int row = i * 16 + srow;
        const int chunk = schunk ^ (row & 7);
        gl_lds16(cg + (size_t)row * ROWB + chunk * 16,
                 ldsB + i * 8192 + (wave << 10));
    }

    // per-thread row stats (same rows every N-tile) — hoisted
    const int il0 = wr * 32 + q * 4;           // fm=0 row base
    const f32x4 xv0 = *(const f32x4*)&x2[mrow0 + il0];
    const f32x4 xv1 = *(const f32x4*)&x2[mrow0 + il0 + 16];

    float* outbase = out + (size_t)mrow0 * KCENT;

    for (int nt = 0; nt < KCENT / BN; ++nt) {
        __syncthreads();   // B[nt] landed (vmcnt drain) + prev readers done

        // ---- 8 K-windows x {6 ds_read_b128 + 8 MFMA} ----
        f32x4 acc[2][4];
#pragma unroll
        for (int fm = 0; fm < 2; ++fm)
#pragma unroll
            for (int fn = 0; fn < 4; ++fn)
                acc[fm][fn] = (f32x4){0.f, 0.f, 0.f, 0.f};

#pragma unroll
        for (int kw = 0; kw < 8; ++kw) {
            FragU a[2], b[4];
#pragma unroll
            for (int fm = 0; fm < 2; ++fm) {
                const int row = wr * 32 + fm * 16 + r16;
                const int chunk = (kw * 4 + q) ^ (row & 7);
                a[fm].u = *(const uint4*)(ldsA + row * ROWB + chunk * 16);
            }
#pragma unroll
            for (int fn = 0; fn < 4; ++fn) {
                const int row = wc * 64 + fn * 16 + r16;
                const int chunk = (kw * 4 + q) ^ (row & 7);
                b[fn].u = *(const uint4*)(ldsB + row * ROWB + chunk * 16);
            }
#pragma unroll
            for (int fm = 0; fm < 2; ++fm)
#pragma unroll
                for (int fn = 0; fn < 4; ++fn)
                    acc[fm][fn] = __builtin_amdgcn_mfma_f32_16x16x32_bf16(
                        a[fm].f, b[fn].f, acc[fm][fn], 0, 0, 0);
        }

        __syncthreads();   // all waves done reading ldsB

        // ---- issue B[nt+1] EARLY: flight hides under the epilogue ----
        if (nt + 1 < KCENT / BN) {
#pragma unroll
            for (int i = 0; i < 8; ++i) {
                const int row = i * 16 + srow;
                const int chunk = schunk ^ (row & 7);
                gl_lds16(cg + (size_t)((nt + 1) * BN + row) * ROWB + chunk * 16,
                         ldsB + i * 8192 + (wave << 10));
            }
        }

        // ---- epilogue (registers + L2-hot stats only; no LDS) ----
        // C/D layout (m89-verified): col = lane&15, row = (lane>>4)*4 + reg
        float* outp = outbase + nt * BN;
#pragma unroll
        for (int fm = 0; fm < 2; ++fm) {
            const int il = il0 + fm * 16;
            const f32x4 xv = fm ? xv1 : xv0;
#pragma unroll
            for (int fn = 0; fn < 4; ++fn) {
                const int j = wc * 64 + fn * 16 + r16;
                const float2 cs = c2s[nt * BN + j];
#pragma unroll
                for (int rg = 0; rg < 4; ++rg) {
                    const float sq = xv[rg] + cs.x - 2.0f * acc[fm][fn][rg];
                    outp[(size_t)(il + rg) * KCENT + j] = __expf(sq * cs.y);
                }
            }
        }
    }
}

extern "C" void kernel_launch(void* const* d_in, const int* in_sizes, int n_in,
                              void* d_out, int out_size, void* d_ws, size_t ws_size,
                              hipStream_t stream) {
    const float* x = (const float*)d_in[0];
    const float* centers = (const float*)d_in[1];
    const float* sigmas = (const float*)d_in[2];
    float* out = (float*)d_out;

    const int Brows = in_sizes[0] / DDIM;  // 32768

    // workspace layout (bytes): xbf | cbf | x2 | c2s  (~17.5 MB total)
    char* ws = (char*)d_ws;
    __bf16* xbf = (__bf16*)ws;
    __bf16* cbf = (__bf16*)(ws + (size_t)Brows * DDIM * 2);
    float* x2 = (float*)(ws + (size_t)Brows * DDIM * 2 + (size_t)KCENT * DDIM * 2);
    float2* c2s = (float2*)((char*)x2 + (size_t)Brows * 4);

    rbf_prep<<<dim3((Brows + KCENT) / 4), dim3(256), 0, stream>>>(
        x, centers, sigmas, xbf, cbf, x2, c2s, Brows);

    rbf_gemm<<<dim3(Brows / BM), dim3(512), 0, stream>>>(xbf, cbf, x2, c2s, out);
}

// Round 10
// 170.054 us; speedup vs baseline: 2.3388x; 1.0610x over previous
//
#include <hip/hip_runtime.h>
#include <hip/hip_bf16.h>

typedef __attribute__((ext_vector_type(8))) __bf16 bf16x8;
typedef __attribute__((ext_vector_type(4))) float f32x4;

#define DDIM 256
#define KCENT 1024
#define BM 64
#define BN 64
#define ROWB 512   // LDS row stride: 256 bf16 = 512 B (full K per row)
#define NTILES (KCENT / BN)   // 16

union FragU { uint4 u; bf16x8 f; };

__device__ __forceinline__ unsigned int pk2(float lo, float hi) {
    union { __hip_bfloat16 h; unsigned short u; } a, b;
    a.h = __float2bfloat16(lo);
    b.h = __float2bfloat16(hi);
    return (unsigned int)a.u | ((unsigned int)b.u << 16);
}

__device__ __forceinline__ void gl_lds16(const void* g, void* l) {
    __builtin_amdgcn_global_load_lds(
        (const __attribute__((address_space(1))) unsigned int*)g,
        (__attribute__((address_space(3))) unsigned int*)l,
        16, 0, 0);
}

// ---------------------------------------------------------------------------
// Kernel 1 (centers only): f32 -> bf16 + exact f32 stats.
// One wave per center row; lane float4 load, shuffle-reduce sumsq.
// ---------------------------------------------------------------------------
__global__ __launch_bounds__(256) void rbf_prep_c(
    const float* __restrict__ centers, const float* __restrict__ sigmas,
    __bf16* __restrict__ cbf, float2* __restrict__ c2s)
{
    const int wave = threadIdx.x >> 6, lane = threadIdx.x & 63;
    const int r = blockIdx.x * 4 + wave;

    const float4* __restrict__ src = (const float4*)(centers + (size_t)r * DDIM);
    const float4 v = src[lane];
    float s = v.x * v.x + v.y * v.y + v.z * v.z + v.w * v.w;
#pragma unroll
    for (int m = 1; m < 64; m <<= 1) s += __shfl_xor(s, m, 64);

    uint2 p;
    p.x = pk2(v.x, v.y);
    p.y = pk2(v.z, v.w);
    ((uint2*)(cbf + (size_t)r * DDIM))[lane] = p;

    if (lane == 0) {
        const float sg = sigmas[r];
        c2s[r] = make_float2(s, -0.5f / (sg * sg));
    }
}

// ---------------------------------------------------------------------------
// Kernel 2 (R8 structure, A-prep coverage fixed): 64-row M-panel per block,
// N-loop inside, 2 blocks/CU (LDS 64KB+stats). 256 threads (4 waves, 2x2 of
// 32x32). Two co-resident blocks = independent barrier domains: one block's
// store-drain overlaps the other's MFMA/LDS phase (m114 overlap; R7's
// 1-block/CU structure serialized these).
// A-prep fused: block converts its own 64 f32 x-rows -> bf16 into ldsA
// (per-lane ds_write, swizzled directly; 4 threads/row x 16 float4 = FULL
// 256-f32 row) + computes x2 in-block via 4-lane shuffle reduce. Kills the
// xbf HBM roundtrip (~33 MB).
// B staging: verified gl_lds16 + pre-swizzled global source (rule #21);
// fragment reads use the identical XOR-low-3 involution on 32 chunks/row
// (0 conflicts, R4/R5/R6/R7). MFMA + C/D mappings verbatim (absmax 0.0, 4x).
// ---------------------------------------------------------------------------
__global__ __launch_bounds__(256, 2) void rbf_gemm(
    const float* __restrict__ x, const __bf16* __restrict__ cbf,
    const float2* __restrict__ c2s, float* __restrict__ out)
{
    __shared__ __align__(16) unsigned char ldsA[BM * ROWB];  // 32 KB
    __shared__ __align__(16) unsigned char ldsB[BN * ROWB];  // 32 KB
    __shared__ float s_x2[BM];

    const int t = threadIdx.x;
    const int lane = t & 63, wave = t >> 6;
    const int wr = wave >> 1, wc = wave & 1;       // 2x2 wave grid, 32x32 each
    const int q = lane >> 4, r16 = lane & 15;
    const int mrow0 = blockIdx.x * BM;

    const char* __restrict__ cg = (const char*)cbf;

    // ---- fused A-prep: 4 threads/row, each 16 float4 (64B runs/instr) ----
    {
        const int ar = t >> 2;          // row 0..63
        const int ac = t & 3;
        const float4* __restrict__ xrow = (const float4*)(x + (size_t)(mrow0 + ar) * DDIM);
        float s = 0.f;
#pragma unroll
        for (int k = 0; k < 16; ++k) {
            const int g = k * 4 + ac;            // float4 index 0..63 (full row)
            const float4 v = xrow[g];
            s += v.x * v.x + v.y * v.y + v.z * v.z + v.w * v.w;
            uint2 p;
            p.x = pk2(v.x, v.y);
            p.y = pk2(v.z, v.w);
            // bf16 8B-half g of row; 16B chunk g>>1 (0..31) swizzled by row&7
            *(uint2*)(ldsA + ar * ROWB + (((g >> 1) ^ (ar & 7)) << 4) + (g & 1) * 8) = p;
        }
        s += __shfl_xor(s, 1, 64);
        s += __shfl_xor(s, 2, 64);
        if (ac == 0) s_x2[ar] = s;
    }

    // ---- stage B[0]: 8 gl_lds issues cover 64 rows x 512 B ----
    // issue i covers LDS [i*4096,+4096): row = i*8 + (t>>5), chunk = t&31.
    const int srow = t >> 5;
    const int schunk = t & 31;
#pragma unroll
    for (int i = 0; i < 8; ++i) {
        const int row = i * 8 + srow;
        const int chunk = schunk ^ (row & 7);
        gl_lds16(cg + (size_t)row * ROWB + chunk * 16,
                 ldsB + i * 4096 + (wave << 10));
    }

    __syncthreads();   // A writes (lgkm) + B[0] (vmcnt) drained

    // row stats to regs (LDS-hot, once)
    const int il0 = wr * 32 + q * 4;
    float xr[2][4];
#pragma unroll
    for (int fm = 0; fm < 2; ++fm)
#pragma unroll
        for (int rg = 0; rg < 4; ++rg)
            xr[fm][rg] = s_x2[il0 + fm * 16 + rg];

    float* outbase = out + (size_t)mrow0 * KCENT;

    for (int nt = 0; nt < NTILES; ++nt) {
        // ---- 8 K-windows x {4 ds_read_b128 + 4 MFMA} ----
        f32x4 acc[2][2];
#pragma unroll
        for (int fm = 0; fm < 2; ++fm)
#pragma unroll
            for (int fn = 0; fn < 2; ++fn)
                acc[fm][fn] = (f32x4){0.f, 0.f, 0.f, 0.f};

#pragma unroll
        for (int kw = 0; kw < 8; ++kw) {
            FragU a[2], b[2];
#pragma unroll
            for (int fm = 0; fm < 2; ++fm) {
                const int row = wr * 32 + fm * 16 + r16;
                const int chunk = (kw * 4 + q) ^ (row & 7);
                a[fm].u = *(const uint4*)(ldsA + row * ROWB + chunk * 16);
            }
#pragma unroll
            for (int fn = 0; fn < 2; ++fn) {
                const int row = wc * 32 + fn * 16 + r16;
                const int chunk = (kw * 4 + q) ^ (row & 7);
                b[fn].u = *(const uint4*)(ldsB + row * ROWB + chunk * 16);
            }
#pragma unroll
            for (int fm = 0; fm < 2; ++fm)
#pragma unroll
                for (int fn = 0; fn < 2; ++fn)
                    acc[fm][fn] = __builtin_amdgcn_mfma_f32_16x16x32_bf16(
                        a[fm].f, b[fn].f, acc[fm][fn], 0, 0, 0);
        }

        __syncthreads();   // all waves done reading ldsB

        // ---- issue B[nt+1] EARLY: flight hides under the epilogue ----
        if (nt + 1 < NTILES) {
#pragma unroll
            for (int i = 0; i < 8; ++i) {
                const int row = i * 8 + srow;
                const int chunk = schunk ^ (row & 7);
                gl_lds16(cg + (size_t)((nt + 1) * BN + row) * ROWB + chunk * 16,
                         ldsB + i * 4096 + (wave << 10));
            }
        }

        // ---- epilogue: sqdist = x2 + c2 - 2*cross; out = exp(scale*sq) ----
        // C/D layout (m89-verified): col = lane&15, row = (lane>>4)*4 + reg
        float* outp = outbase + nt * BN;
#pragma unroll
        for (int fm = 0; fm < 2; ++fm) {
            const int il = il0 + fm * 16;
#pragma unroll
            for (int fn = 0; fn < 2; ++fn) {
                const int j = wc * 32 + fn * 16 + r16;
                const float2 cs = c2s[nt * BN + j];
#pragma unroll
                for (int rg = 0; rg < 4; ++rg) {
                    const float sq = xr[fm][rg] + cs.x - 2.0f * acc[fm][fn][rg];
                    outp[(size_t)(il + rg) * KCENT + j] = __expf(sq * cs.y);
                }
            }
        }

        __syncthreads();   // B[nt+1] landed; ldsB safe to read next iter
    }
}

extern "C" void kernel_launch(void* const* d_in, const int* in_sizes, int n_in,
                              void* d_out, int out_size, void* d_ws, size_t ws_size,
                              hipStream_t stream) {
    const float* x = (const float*)d_in[0];
    const float* centers = (const float*)d_in[1];
    const float* sigmas = (const float*)d_in[2];
    float* out = (float*)d_out;

    const int Brows = in_sizes[0] / DDIM;  // 32768

    // workspace layout: cbf (512 KB) | c2s (8 KB)
    char* ws = (char*)d_ws;
    __bf16* cbf = (__bf16*)ws;
    float2* c2s = (float2*)(ws + (size_t)KCENT * DDIM * 2);

    rbf_prep_c<<<dim3(KCENT / 4), dim3(256), 0, stream>>>(centers, sigmas, cbf, c2s);
    rbf_gemm<<<dim3(Brows / BM), dim3(256), 0, stream>>>(x, cbf, c2s, out);
}